// Round 10
// baseline (302.180 us; speedup 1.0000x reference)
//
#include <hip/hip_runtime.h>
#include <hip/hip_bf16.h>

#define NT 256
#define TT 96       // mus/gen_z outputs per tile
#define NTILE 171   // ceil(T/TT)
#define PBA 126     // bufA rows (L0/L2 output)
#define PBB 124     // bufB rows (L1/L3 output)
#define NB 16
#define T_ 16384
#define W_ 32
#define TW_ (T_ - W_)
#define SLOPE_C 0.22916666666666666f

// weight image in workspace (ushort offsets), UNSWIZZLED rows of 64:
//   0      : W1 hi[8192] lo[8192]   16384: W2   32768: W3
//   49152  : W4 hi[2048] lo[2048] (rows 8..15 of each k zeroed)
//   53248  : consts float[1536]
#define WIMG_W4   49152
#define WIMG_CST  53248
#define WIMG_USH  56320

typedef short v8s __attribute__((ext_vector_type(8)));
typedef float v4f __attribute__((ext_vector_type(4)));

__device__ __forceinline__ float rr(float v){ return v >= 0.f ? v : v * SLOPE_C; }
__device__ __forceinline__ ushort f2bs(float f){ __hip_bfloat16 h = __float2bfloat16(f); return *(ushort*)&h; }
__device__ __forceinline__ float bs2f(ushort u){ union{unsigned i; float f;} v; v.i = ((unsigned)u) << 16; return v.f; }

// swizzled fp32-pair act addressing: row = 128 ushorts ([hi 64][lo 64]) = 16 granules
__device__ __forceinline__ int agr(int p, int gi){ return p*128 + ((gi ^ (p & 15)) << 3); }

// ---------------- pre-kernel: build hi/lo weight image ----------------
__global__ __launch_bounds__(256) void kW(
    const float* __restrict__ cw1, const float* __restrict__ cw2,
    const float* __restrict__ cw3, const float* __restrict__ cw4,
    const float* __restrict__ cw0, const float* __restrict__ cb0,
    const float* __restrict__ cb1, const float* __restrict__ cb2,
    const float* __restrict__ cb3, const float* __restrict__ cb4,
    const float* __restrict__ mw0, const float* __restrict__ mb0,
    const float* __restrict__ mw1, const float* __restrict__ mb1,
    const float* __restrict__ mw2, const float* __restrict__ mb2,
    const float* __restrict__ fish, const float* __restrict__ sct,
    ushort* __restrict__ wimg)
{
  const int id = blockIdx.x*256 + threadIdx.x;
  if (id < 24576){                       // W1..W3: (64,64,2) each
    int l = id >> 13, e = id & 8191;
    const float* src = (l == 0) ? cw1 : ((l == 1) ? cw2 : cw3);
    int c = e >> 7, rem = e & 127, ci = rem >> 1, k = rem & 1;
    float v = src[e];
    ushort h = f2bs(v), lo = f2bs(v - bs2f(h));
    int ix = (k*64 + c)*64 + ci;
    wimg[l*16384 + ix] = h;
    wimg[l*16384 + 8192 + ix] = lo;
  } else if (id < 25600){                // W4: (8,64,2), rows 0..7
    int e = id - 24576;
    int c = e >> 7, rem = e & 127, ci = rem >> 1, k = rem & 1;
    float v = cw4[e];
    ushort h = f2bs(v), lo = f2bs(v - bs2f(h));
    int ix = (k*16 + c)*64 + ci;
    wimg[WIMG_W4 + ix] = h;
    wimg[WIMG_W4 + 2048 + ix] = lo;
  } else if (id < 27648){                // W4: zero rows m=8..15, both planes
    int e = id - 25600;
    int pl = e >> 10, rem = e & 1023, k = rem >> 9, r2 = rem & 511;
    int m = 8 + (r2 >> 6), ci = r2 & 63;
    wimg[WIMG_W4 + pl*2048 + (k*16 + m)*64 + ci] = 0;
  } else if (id < 29184){                // consts float[1536]
    int e = id - 27648;
    float v = 0.f;
    if      (e < 256)  v = mw0[e];
    else if (e < 512)  v = mw1[e - 256];
    else if (e < 528)  v = mw2[e - 512];
    else if (e < 544)  v = mb0[e - 528];
    else if (e < 560)  v = mb1[e - 544];
    else if (e < 561)  v = mb2[0];
    else if (e >= 576 && e < 584)  v = cb4[e - 576];
    else if (e >= 592 && e < 720)  v = cw0[e - 592];
    else if (e >= 720 && e < 784)  v = cb0[e - 720];
    else if (e >= 784 && e < 848)  v = cb1[e - 784];
    else if (e >= 848 && e < 912)  v = cb2[e - 848];
    else if (e >= 912 && e < 976)  v = cb3[e - 912];
    else if (e >= 1024 && e < 1280) v = fish[e - 1024];
    else if (e >= 1280 && e < 1288) v = sct[e - 1280];
    ((float*)(wimg + WIMG_CST))[e] = v;
  }
}

// 64->64 dilated conv on MFMA, hi/lo bf16 (3-term); weights from GLOBAL.
// All 4 waves compute; wave w covers positions [w*32, w*32+32).
template<int D, int NSRC, int NDST>
__device__ __forceinline__ void mfma_layer(const ushort* __restrict__ src,
    ushort* __restrict__ dst, const ushort* __restrict__ wg,
    const float* __restrict__ cbias, int tid)
{
  const int wave = tid >> 6;
  const int lane = tid & 63;
  const int n = lane & 15, quad = lane >> 4;
  const int p0 = wave * 32;

  v4f acc[8];
  const v4f vz = {0.f, 0.f, 0.f, 0.f};
#pragma unroll
  for (int i = 0; i < 8; ++i) acc[i] = vz;

#pragma unroll
  for (int tap = 0; tap < 2; ++tap){
#pragma unroll
    for (int kb = 0; kb < 2; ++kb){
      const int kg = kb*4 + quad;
      v8s wh[4], wl[4], ah[2], al[2];
#pragma unroll
      for (int mt = 0; mt < 4; ++mt){
        int base = (tap*64 + mt*16 + n)*64 + kg*8;
        wh[mt] = *(const v8s*)(wg + base);
        wl[mt] = *(const v8s*)(wg + 8192 + base);
      }
#pragma unroll
      for (int nt = 0; nt < 2; ++nt){
        int p = p0 + nt*16 + n + tap*D;
        if (p >= NSRC) p = NSRC - 1;            // clamp: invalid outputs only
        ah[nt] = *(const v8s*)(src + agr(p, kg));
        al[nt] = *(const v8s*)(src + agr(p, 8 + kg));
      }
#pragma unroll
      for (int nt = 0; nt < 2; ++nt)
#pragma unroll
        for (int mt = 0; mt < 4; ++mt){
          v4f a = acc[nt*4 + mt];
          a = __builtin_amdgcn_mfma_f32_16x16x32_bf16(wh[mt], ah[nt], a, 0, 0, 0);
          a = __builtin_amdgcn_mfma_f32_16x16x32_bf16(wh[mt], al[nt], a, 0, 0, 0);
          a = __builtin_amdgcn_mfma_f32_16x16x32_bf16(wl[mt], ah[nt], a, 0, 0, 0);
          acc[nt*4 + mt] = a;
        }
    }
  }

  // epilogue: D col=lane&15 (pos), row=quad*4+r (cout)
#pragma unroll
  for (int nt = 0; nt < 2; ++nt){
    int p = p0 + nt*16 + n;
    if (p < NDST){
#pragma unroll
      for (int mt = 0; mt < 4; ++mt){
#pragma unroll
        for (int r = 0; r < 4; r += 2){
          int c = mt*16 + quad*4 + r;
          float y0 = rr(acc[nt*4 + mt][r]     + cbias[c]);
          float y1 = rr(acc[nt*4 + mt][r + 1] + cbias[c + 1]);
          ushort h0 = f2bs(y0), h1 = f2bs(y1);
          ushort l0 = f2bs(y0 - bs2f(h0)), l1 = f2bs(y1 - bs2f(h1));
          *(unsigned*)(dst + agr(p, c >> 3)       + (c & 7)) = (unsigned)h0 | ((unsigned)h1 << 16);
          *(unsigned*)(dst + agr(p, 8 + (c >> 3)) + (c & 7)) = (unsigned)l0 | ((unsigned)l1 << 16);
        }
      }
    }
  }
}

__global__ __launch_bounds__(NT, 2) void kA(
    const float* __restrict__ x, const float* __restrict__ gum,
    const ushort* __restrict__ wimg,
    float* __restrict__ ws_mus, float* __restrict__ out_gz)
{
  __shared__ __align__(16) ushort bufA[PBA*128];   // 32,256 B
  __shared__ __align__(16) ushort bufB[PBB*128];   // 31,744 B
  __shared__ __align__(16) float  cstl[1536];      //  6,144 B -> 70,144 B (2 blocks/CU)

  float* xbuf = (float*)bufB;            // alias: dead before L1 writes bufB
  float* h4s  = (float*)bufA;            // overlay after L3 (L2 data dead): [8][TT]

  const int tile = blockIdx.x, b = blockIdx.y;
  const int o0 = tile * TT;
  const int core = (T_ - o0 < TT) ? (T_ - o0) : TT;
  const int tid = threadIdx.x;

  // Phase A: stage x + consts
  const int nx = core + 31;
  for (int i = tid; i < nx; i += NT){
    int g = o0 + i;
    xbuf[i] = (g >= 31) ? x[(size_t)b*T_ + g - 31] : 0.f;
  }
  for (int i = tid; i < 768; i += NT)
    ((float2*)cstl)[i] = ((const float2*)(wimg + WIMG_CST))[i];
  __syncthreads();

  // Layer0 (1->64, d=1): paired u32 writes, zero-fill halo
  {
    const int n0 = core + 30;
    for (int i = tid; i < PBA*32; i += NT){
      int p = i >> 5, c = (i & 31)*2;
      float y0 = 0.f, y1 = 0.f;
      if (p < n0){
        float xp = xbuf[p], xq = xbuf[p + 1];
        y0 = rr(cstl[720 + c]     + cstl[592 + 2*c]*xp + cstl[593 + 2*c]*xq);
        y1 = rr(cstl[720 + c + 1] + cstl[594 + 2*c]*xp + cstl[595 + 2*c]*xq);
      }
      ushort h0 = f2bs(y0), h1 = f2bs(y1);
      ushort l0 = f2bs(y0 - bs2f(h0)), l1 = f2bs(y1 - bs2f(h1));
      *(unsigned*)(bufA + agr(p, c >> 3)       + (c & 7)) = (unsigned)h0 | ((unsigned)h1 << 16);
      *(unsigned*)(bufA + agr(p, 8 + (c >> 3)) + (c & 7)) = (unsigned)l0 | ((unsigned)l1 << 16);
    }
  }
  __syncthreads();

  mfma_layer<2, PBA, PBB>(bufA, bufB, wimg,         cstl + 784, tid);  // L1
  __syncthreads();
  mfma_layer<4, PBB, 120>(bufB, bufA, wimg + 16384, cstl + 848, tid);  // L2
  __syncthreads();
  mfma_layer<8, 120, 112>(bufA, bufB, wimg + 32768, cstl + 912, tid);  // L3
  __syncthreads();

  // Layer4 (64->8, d=16) on MFMA: M=16 tile, rows 8..15 zero; weights global
  {
    const ushort* wg4 = wimg + WIMG_W4;
    const int wave = tid >> 6;
    const int lane = tid & 63;
    const int n = lane & 15, quad = lane >> 4;
    const int p0 = wave * 32;
    v4f acc2[2];
    const v4f vz = {0.f, 0.f, 0.f, 0.f};
    acc2[0] = vz; acc2[1] = vz;
#pragma unroll
    for (int tap = 0; tap < 2; ++tap){
#pragma unroll
      for (int kb = 0; kb < 2; ++kb){
        const int kg = kb*4 + quad;
        int base = (tap*16 + n)*64 + kg*8;
        v8s wh = *(const v8s*)(wg4 + base);
        v8s wl = *(const v8s*)(wg4 + 2048 + base);
#pragma unroll
        for (int nt = 0; nt < 2; ++nt){
          int p = p0 + nt*16 + n + tap*16;
          if (p >= 112) p = 111;               // valid L3 rows only
          v8s ah = *(const v8s*)(bufB + agr(p, kg));
          v8s al = *(const v8s*)(bufB + agr(p, 8 + kg));
          v4f a = acc2[nt];
          a = __builtin_amdgcn_mfma_f32_16x16x32_bf16(wh, ah, a, 0, 0, 0);
          a = __builtin_amdgcn_mfma_f32_16x16x32_bf16(wh, al, a, 0, 0, 0);
          a = __builtin_amdgcn_mfma_f32_16x16x32_bf16(wl, ah, a, 0, 0, 0);
          acc2[nt] = a;
        }
      }
    }
    __syncthreads();                           // bufA (L2) fully consumed; reuse as h4s
#pragma unroll
    for (int nt = 0; nt < 2; ++nt){
      int p = p0 + nt*16 + n;
      if (p < core && quad < 2){
#pragma unroll
        for (int r = 0; r < 4; ++r){
          int c = quad*4 + r;
          h4s[c*TT + p] = rr(acc2[nt][r] + cstl[576 + c]);
        }
      }
    }
  }
  __syncthreads();

  // Phase J: softmax + pointwise MLP
  if (tid < core){
    const int t = o0 + tid;
    float l[8];
#pragma unroll
    for (int r = 0; r < 8; ++r) l[r] = h4s[r*TT + tid];
    float gv[8];
    *(float4*)&gv[0] = *(const float4*)(gum + (size_t)(b*T_ + t)*8);
    *(float4*)&gv[4] = *(const float4*)(gum + (size_t)(b*T_ + t)*8 + 4);
    float s[8], mx = -1e30f;
#pragma unroll
    for (int r = 0; r < 8; ++r){ s[r] = (l[r] + gv[r]) * 10.0f; mx = fmaxf(mx, s[r]); }
    float e[8], sum = 0.f;
#pragma unroll
    for (int r = 0; r < 8; ++r){ e[r] = __expf(s[r] - mx); sum += e[r]; }
    float inv = 1.0f / sum;
    float z[8];
#pragma unroll
    for (int r = 0; r < 8; ++r){
      z[r] = e[r] * inv;
      out_gz[(size_t)(b*8 + r)*T_ + t] = z[r];
    }
    float m0[16];
#pragma unroll
    for (int o = 0; o < 16; ++o){
      float a = cstl[528 + o];
#pragma unroll
      for (int i = 0; i < 8; ++i) a += cstl[o*16 + i] * z[i];
#pragma unroll
      for (int i = 0; i < 8; ++i) a += cstl[o*16 + 8 + i] * l[i];
      m0[o] = rr(a);
    }
    float m1[16];
#pragma unroll
    for (int o = 0; o < 16; ++o){
      float a = cstl[544 + o];
#pragma unroll
      for (int i = 0; i < 16; ++i) a += cstl[256 + o*16 + i] * m0[i];
      m1[o] = rr(a);
    }
    float mu = cstl[560];
#pragma unroll
    for (int i = 0; i < 16; ++i) mu += cstl[512 + i] * m1[i];
    ws_mus[(size_t)b*T_ + t] = mu;
  }
}

__global__ __launch_bounds__(256) void kB(
    const float* __restrict__ x, const float* __restrict__ fish,
    const float* __restrict__ sct, const float* __restrict__ ws_mus,
    const float* __restrict__ gz, float* __restrict__ out0)
{
  __shared__ float xm[288], mm[288], fs[256], sc[8];
  const int b = blockIdx.y;
  const int s = blockIdx.x * 256;
  const int tid = threadIdx.x;
  for (int i = tid; i < 288; i += 256){
    int g = s + i;
    bool ok = g < T_;
    xm[i] = ok ? x[(size_t)b*T_ + g] : 0.f;
    mm[i] = ok ? ws_mus[(size_t)b*T_ + g] : 0.f;
  }
  fs[tid] = fish[tid];
  if (tid < 8) sc[tid] = sct[tid];
  __syncthreads();
  const int tp = s + tid;
  if (tp < TW_){
    const int t = W_ + tp;
    float z[8];
#pragma unroll
    for (int r = 0; r < 8; ++r) z[r] = gz[(size_t)(b*8 + r)*T_ + t];
    float cv = 0.f;
#pragma unroll
    for (int r = 0; r < 8; ++r) cv += sc[r] * z[r];
    cv *= cv;
    float acc = 0.f;
#pragma unroll 4
    for (int w = 0; w < 32; ++w){
      float fj = 0.f;
#pragma unroll
      for (int r = 0; r < 8; ++r) fj += z[r] * fs[r*32 + w];
      acc += fj * (xm[tid + w] - mm[tid + w]);
    }
    out0[(size_t)b*TW_ + tp] = mm[tid + 32] - cv * acc;
  }
}

extern "C" void kernel_launch(void* const* d_in, const int* in_sizes, int n_in,
                              void* d_out, int out_size, void* d_ws, size_t ws_size,
                              hipStream_t stream)
{
  const float* x   = (const float*)d_in[0];
  const float* cw0 = (const float*)d_in[1];
  const float* cb0 = (const float*)d_in[2];
  const float* cw1 = (const float*)d_in[3];
  const float* cb1 = (const float*)d_in[4];
  const float* cw2 = (const float*)d_in[5];
  const float* cb2 = (const float*)d_in[6];
  const float* cw3 = (const float*)d_in[7];
  const float* cb3 = (const float*)d_in[8];
  const float* cw4 = (const float*)d_in[9];
  const float* cb4 = (const float*)d_in[10];
  const float* mw0 = (const float*)d_in[11];
  const float* mb0 = (const float*)d_in[12];
  const float* mw1 = (const float*)d_in[13];
  const float* mb1 = (const float*)d_in[14];
  const float* mw2 = (const float*)d_in[15];
  const float* mb2 = (const float*)d_in[16];
  const float* sct = (const float*)d_in[17];
  const float* fish= (const float*)d_in[18];
  const float* gum = (const float*)d_in[19];

  float* out0   = (float*)d_out;               // _mus: (16, 16352)
  float* out_gz = out0 + NB*TW_;               // gen_z: (16, 8, 16384)
  ushort* wimg  = (ushort*)d_ws;               // weight image (112,640 B)
  float* ws_mus = (float*)((char*)d_ws + 131072);   // 1 MB mus

  kW<<<114, 256, 0, stream>>>(cw1, cw2, cw3, cw4, cw0, cb0, cb1, cb2, cb3, cb4,
                              mw0, mb0, mw1, mb1, mw2, mb2, fish, sct, wimg);

  dim3 gA(NTILE, NB);                          // (171, 16)
  kA<<<gA, NT, 0, stream>>>(x, gum, wimg, ws_mus, out_gz);
  dim3 gB((TW_ + 255) / 256, NB);              // (64, 16)
  kB<<<gB, 256, 0, stream>>>(x, fish, sct, ws_mus, out_gz, out0);
}

// Round 12
// 214.762 us; speedup vs baseline: 1.4070x; 1.4070x over previous
//
#include <hip/hip_runtime.h>
#include <hip/hip_bf16.h>

#define NT 512
#define TT 160      // outputs per tile
#define NTILE 103   // ceil(T/TT)
#define RA 190      // bufA rows (TT+30)
#define RB 188      // bufB rows (TT+28)
#define NB 16
#define T_ 16384
#define W_ 32
#define TW_ (T_ - W_)
#define SLOPE_C 0.22916666666666666f

// weight image in workspace (ushort offsets), SWIZZLED rows:
//   0: W1 hi/lo   16384: W2   32768: W3   49152: W4 (rows 8..15 zeroed)
//   53248: consts float[1536]
#define WIMG_W4   49152
#define WIMG_CST  53248

typedef short v8s __attribute__((ext_vector_type(8)));
typedef float v4f __attribute__((ext_vector_type(4)));

__device__ __forceinline__ float rr(float v){ return v >= 0.f ? v : v * SLOPE_C; }
__device__ __forceinline__ ushort f2bs(float f){ __hip_bfloat16 h = __float2bfloat16(f); return *(ushort*)&h; }
__device__ __forceinline__ float bs2f(ushort u){ union{unsigned i; float f;} v; v.i = ((unsigned)u) << 16; return v.f; }

__device__ __forceinline__ int agr(int p, int gi){ return p*128 + ((gi ^ (p & 15)) << 3); }
__device__ __forceinline__ int widx(int wr, int ci){
  return wr*64 + ((((ci >> 3) ^ (wr & 7)) << 3) | (ci & 7));
}

// ---------------- pre-kernel: swizzled hi/lo weight image + consts ----------------
__global__ __launch_bounds__(256) void kW(
    const float* __restrict__ cw1, const float* __restrict__ cw2,
    const float* __restrict__ cw3, const float* __restrict__ cw4,
    const float* __restrict__ cw0, const float* __restrict__ cb0,
    const float* __restrict__ cb1, const float* __restrict__ cb2,
    const float* __restrict__ cb3, const float* __restrict__ cb4,
    const float* __restrict__ mw0, const float* __restrict__ mb0,
    const float* __restrict__ mw1, const float* __restrict__ mb1,
    const float* __restrict__ mw2, const float* __restrict__ mb2,
    const float* __restrict__ fish, const float* __restrict__ sct,
    ushort* __restrict__ wimg)
{
  const int id = blockIdx.x*256 + threadIdx.x;
  if (id < 24576){                       // W1..W3: (64,64,2)
    int l = id >> 13, e = id & 8191;
    const float* src = (l == 0) ? cw1 : ((l == 1) ? cw2 : cw3);
    int c = e >> 7, rem = e & 127, ci = rem >> 1, k = rem & 1;
    float v = src[e];
    ushort h = f2bs(v), lo = f2bs(v - bs2f(h));
    int ix = widx(k*64 + c, ci);
    wimg[l*16384 + ix] = h;
    wimg[l*16384 + 8192 + ix] = lo;
  } else if (id < 25600){                // W4 rows 0..7
    int e = id - 24576;
    int c = e >> 7, rem = e & 127, ci = rem >> 1, k = rem & 1;
    float v = cw4[e];
    ushort h = f2bs(v), lo = f2bs(v - bs2f(h));
    int ix = widx(k*16 + c, ci);
    wimg[WIMG_W4 + ix] = h;
    wimg[WIMG_W4 + 2048 + ix] = lo;
  } else if (id < 27648){                // W4 zero rows 8..15
    int e = id - 25600;
    int pl = e >> 10, rem = e & 1023, k = rem >> 9, r2 = rem & 511;
    int m = 8 + (r2 >> 6), ci = r2 & 63;
    wimg[WIMG_W4 + pl*2048 + widx(k*16 + m, ci)] = 0;
  } else if (id < 29184){                // consts float[1536]
    int e = id - 27648;
    float v = 0.f;
    if      (e < 256)  v = mw0[e];
    else if (e < 512)  v = mw1[e - 256];
    else if (e < 528)  v = mw2[e - 512];
    else if (e < 544)  v = mb0[e - 528];
    else if (e < 560)  v = mb1[e - 544];
    else if (e < 561)  v = mb2[0];
    else if (e >= 576 && e < 584)  v = cb4[e - 576];
    else if (e >= 592 && e < 720)  v = cw0[e - 592];
    else if (e >= 720 && e < 784)  v = cb0[e - 720];
    else if (e >= 784 && e < 848)  v = cb1[e - 784];
    else if (e >= 848 && e < 912)  v = cb2[e - 848];
    else if (e >= 912 && e < 976)  v = cb3[e - 912];
    else if (e >= 1024 && e < 1280) v = fish[e - 1024];
    else if (e >= 1280 && e < 1288) v = sct[e - 1280];
    ((float*)(wimg + WIMG_CST))[e] = v;
  }
}

// 64->64 dilated conv on MFMA, hi/lo bf16 (3-term), weights from swizzled LDS.
// Caller guards: only waves 0..5 enter. Wave w covers positions [w*32, w*32+32).
template<int D, int NSRC, int NDST>
__device__ __forceinline__ void mfma_layer(const ushort* __restrict__ src,
    ushort* __restrict__ dst, const ushort* __restrict__ wlds,
    const float* __restrict__ cbias, int tid)
{
  const int wave = tid >> 6;
  const int lane = tid & 63;
  const int n = lane & 15, quad = lane >> 4;
  const int p0 = wave * 32;

  v4f acc[8];
  const v4f vz = {0.f, 0.f, 0.f, 0.f};
#pragma unroll
  for (int i = 0; i < 8; ++i) acc[i] = vz;

#pragma unroll
  for (int tap = 0; tap < 2; ++tap){
#pragma unroll
    for (int kb = 0; kb < 2; ++kb){
      const int kg = kb*4 + quad;
      v8s wh[4], wl[4], ah[2], al[2];
#pragma unroll
      for (int mt = 0; mt < 4; ++mt){
        int wr = tap*64 + mt*16 + n;
        int base = wr*64 + ((kg ^ (wr & 7)) << 3);
        wh[mt] = *(const v8s*)(wlds + base);
        wl[mt] = *(const v8s*)(wlds + 8192 + base);
      }
#pragma unroll
      for (int nt = 0; nt < 2; ++nt){
        int p = p0 + nt*16 + n + tap*D;
        if (p >= NSRC) p = NSRC - 1;            // clamp: invalid outputs only
        ah[nt] = *(const v8s*)(src + agr(p, kg));
        al[nt] = *(const v8s*)(src + agr(p, 8 + kg));
      }
#pragma unroll
      for (int nt = 0; nt < 2; ++nt)
#pragma unroll
        for (int mt = 0; mt < 4; ++mt){
          v4f a = acc[nt*4 + mt];
          a = __builtin_amdgcn_mfma_f32_16x16x32_bf16(wh[mt], ah[nt], a, 0, 0, 0);
          a = __builtin_amdgcn_mfma_f32_16x16x32_bf16(wh[mt], al[nt], a, 0, 0, 0);
          a = __builtin_amdgcn_mfma_f32_16x16x32_bf16(wl[mt], ah[nt], a, 0, 0, 0);
          acc[nt*4 + mt] = a;
        }
    }
  }

#pragma unroll
  for (int nt = 0; nt < 2; ++nt){
    int p = p0 + nt*16 + n;
    if (p < NDST){
#pragma unroll
      for (int mt = 0; mt < 4; ++mt){
#pragma unroll
        for (int r = 0; r < 4; r += 2){
          int c = mt*16 + quad*4 + r;
          float y0 = rr(acc[nt*4 + mt][r]     + cbias[c]);
          float y1 = rr(acc[nt*4 + mt][r + 1] + cbias[c + 1]);
          ushort h0 = f2bs(y0), h1 = f2bs(y1);
          ushort l0 = f2bs(y0 - bs2f(h0)), l1 = f2bs(y1 - bs2f(h1));
          *(unsigned*)(dst + agr(p, c >> 3)       + (c & 7)) = (unsigned)h0 | ((unsigned)h1 << 16);
          *(unsigned*)(dst + agr(p, 8 + (c >> 3)) + (c & 7)) = (unsigned)l0 | ((unsigned)l1 << 16);
        }
      }
    }
  }
}

// stager: linear 16B copy global image -> LDS, 128 threads
__device__ __forceinline__ void stageW(ushort* dst, const ushort* src, int n8, int t128){
  for (int i = t128; i < n8; i += 128)
    *(v8s*)(dst + i*8) = *(const v8s*)(src + i*8);
}

__global__ __launch_bounds__(NT) void kA(
    const float* __restrict__ x, const ushort* __restrict__ wimg,
    float* __restrict__ h4ws)
{
  __shared__ __align__(16) ushort bufA[RA*128];    // 48,640 B
  __shared__ __align__(16) ushort bufB[RB*128];    // 48,128 B
  __shared__ __align__(16) ushort r1[16384];       // 32,768 B
  __shared__ __align__(16) ushort r2[16384];       // 32,768 B
  __shared__ __align__(16) float  cst[264];        //  1,056 B  -> 163,360 B

  const float* cstf = (const float*)(wimg + WIMG_CST);
  float* xbuf = (float*)bufB;            // alias: dead before L1 writes bufB

  const int tile = blockIdx.x, b = blockIdx.y;
  const int o0 = tile * TT;
  const int core = (T_ - o0 < TT) ? (T_ - o0) : TT;
  const int tid = threadIdx.x;
  const int wave = tid >> 6;

  // Phase A: stage x, W1->r1, biases
  const int nx = core + 31;
  for (int i = tid; i < nx; i += NT){
    int g = o0 + i;
    xbuf[i] = (g >= 31) ? x[(size_t)b*T_ + g - 31] : 0.f;
  }
  for (int i = tid; i < 2048; i += NT)
    *(v8s*)(r1 + i*8) = *(const v8s*)(wimg + i*8);
  for (int i = tid; i < 264; i += NT){
    float v;
    if (i < 192) v = cstf[784 + i];            // cb1,cb2,cb3
    else if (i < 200) v = cstf[576 + i - 192]; // cb4
    else v = cstf[720 + i - 200];              // cb0
    cst[i] = v;
  }
  __syncthreads();

  // Layer0 (1->64, d=1): paired u32 writes, zero halo; cw0 from global (L2-hot)
  {
    const int n0 = core + 30;
    for (int i = tid; i < RA*32; i += NT){
      int p = i >> 5, c = (i & 31)*2;
      float y0 = 0.f, y1 = 0.f;
      if (p < n0){
        float xp = xbuf[p], xq = xbuf[p + 1];
        y0 = rr(cst[200 + c]     + cstf[592 + 2*c]*xp + cstf[593 + 2*c]*xq);
        y1 = rr(cst[201 + c]     + cstf[594 + 2*c]*xp + cstf[595 + 2*c]*xq);
      }
      ushort h0 = f2bs(y0), h1 = f2bs(y1);
      ushort l0 = f2bs(y0 - bs2f(h0)), l1 = f2bs(y1 - bs2f(h1));
      *(unsigned*)(bufA + agr(p, c >> 3)       + (c & 7)) = (unsigned)h0 | ((unsigned)h1 << 16);
      *(unsigned*)(bufA + agr(p, 8 + (c >> 3)) + (c & 7)) = (unsigned)l0 | ((unsigned)l1 << 16);
    }
  }
  __syncthreads();

  // L1 compute (r1) || stage W2->r2
  if (wave < 6) mfma_layer<2, RA, RB>(bufA, bufB, r1, cst, tid);
  else          stageW(r2, wimg + 16384, 2048, tid - 384);
  __syncthreads();
  // L2 compute (r2) || stage W3->r1   [NSRC=188 = L1's NDST — R11 bug was 184]
  if (wave < 6) mfma_layer<4, 188, 184>(bufB, bufA, r2, cst + 64, tid);
  else          stageW(r1, wimg + 32768, 2048, tid - 384);
  __syncthreads();
  // L3 compute (r1) || stage W4->r2
  if (wave < 6) mfma_layer<8, 184, 176>(bufA, bufB, r1, cst + 128, tid);
  else          stageW(r2, wimg + WIMG_W4, 512, tid - 384);
  __syncthreads();

  // Layer4 (64->8, d=16) on MFMA from r2; epilogue straight to global h4ws
  if (wave < 5){
    const int lane = tid & 63;
    const int n = lane & 15, quad = lane >> 4;
    const int p0 = wave * 32;
    v4f acc2[2];
    const v4f vz = {0.f, 0.f, 0.f, 0.f};
    acc2[0] = vz; acc2[1] = vz;
#pragma unroll
    for (int tap = 0; tap < 2; ++tap){
#pragma unroll
      for (int kb = 0; kb < 2; ++kb){
        const int kg = kb*4 + quad;
        int wr = tap*16 + n;
        int base = wr*64 + ((kg ^ (wr & 7)) << 3);
        v8s wh = *(const v8s*)(r2 + base);
        v8s wl = *(const v8s*)(r2 + 2048 + base);
#pragma unroll
        for (int nt = 0; nt < 2; ++nt){
          int p = p0 + nt*16 + n + tap*16;
          if (p >= 176) p = 175;
          v8s ah = *(const v8s*)(bufB + agr(p, kg));
          v8s al = *(const v8s*)(bufB + agr(p, 8 + kg));
          v4f a = acc2[nt];
          a = __builtin_amdgcn_mfma_f32_16x16x32_bf16(wh, ah, a, 0, 0, 0);
          a = __builtin_amdgcn_mfma_f32_16x16x32_bf16(wh, al, a, 0, 0, 0);
          a = __builtin_amdgcn_mfma_f32_16x16x32_bf16(wl, ah, a, 0, 0, 0);
          acc2[nt] = a;
        }
      }
    }
#pragma unroll
    for (int nt = 0; nt < 2; ++nt){
      int p = p0 + nt*16 + n;
      if (p < core && quad < 2){
#pragma unroll
        for (int r = 0; r < 4; ++r){
          int c = quad*4 + r;
          h4ws[(size_t)(b*8 + c)*T_ + o0 + p] = rr(acc2[nt][r] + cst[192 + c]);
        }
      }
    }
  }
}

// softmax + MLP + windowed correction; MLP/fish/sct via uniform global (s_load)
__global__ __launch_bounds__(256) void kB2(
    const float* __restrict__ x, const float* __restrict__ gum,
    const float* __restrict__ h4, const float* __restrict__ cstf,
    float* __restrict__ out0, float* __restrict__ out_gz)
{
  __shared__ float xm[288];
  __shared__ float mm[288];
  __shared__ float zz[288*9];
  const int b = blockIdx.y;
  const int s = blockIdx.x * 256;
  const int tid = threadIdx.x;

  for (int i = tid; i < 288; i += 256){
    int g = s + i;
    xm[i] = (g < T_) ? x[(size_t)b*T_ + g] : 0.f;
  }

#pragma unroll
  for (int pass = 0; pass < 2; ++pass){
    int j = pass == 0 ? tid : 256 + tid;
    if (pass == 1 && tid >= 32) break;
    int t = s + j;
    if (t < T_){
      float l[8];
#pragma unroll
      for (int r = 0; r < 8; ++r) l[r] = h4[(size_t)(b*8 + r)*T_ + t];
      float gv[8];
      *(float4*)&gv[0] = *(const float4*)(gum + (size_t)(b*T_ + t)*8);
      *(float4*)&gv[4] = *(const float4*)(gum + (size_t)(b*T_ + t)*8 + 4);
      float sv[8], mx = -1e30f;
#pragma unroll
      for (int r = 0; r < 8; ++r){ sv[r] = (l[r] + gv[r]) * 10.0f; mx = fmaxf(mx, sv[r]); }
      float e[8], sum = 0.f;
#pragma unroll
      for (int r = 0; r < 8; ++r){ e[r] = __expf(sv[r] - mx); sum += e[r]; }
      float inv = 1.0f / sum;
      float z[8];
#pragma unroll
      for (int r = 0; r < 8; ++r){
        z[r] = e[r] * inv;
        out_gz[(size_t)(b*8 + r)*T_ + t] = z[r];
        zz[j*9 + r] = z[r];
      }
      float m0[16];
#pragma unroll
      for (int o = 0; o < 16; ++o){
        float a = cstf[528 + o];
#pragma unroll
        for (int i = 0; i < 8; ++i) a += cstf[o*16 + i] * z[i];
#pragma unroll
        for (int i = 0; i < 8; ++i) a += cstf[o*16 + 8 + i] * l[i];
        m0[o] = rr(a);
      }
      float m1[16];
#pragma unroll
      for (int o = 0; o < 16; ++o){
        float a = cstf[544 + o];
#pragma unroll
        for (int i = 0; i < 16; ++i) a += cstf[256 + o*16 + i] * m0[i];
        m1[o] = rr(a);
      }
      float mu = cstf[560];
#pragma unroll
      for (int i = 0; i < 16; ++i) mu += cstf[512 + i] * m1[i];
      mm[j] = mu;
    } else {
      mm[j] = 0.f;
#pragma unroll
      for (int r = 0; r < 8; ++r) zz[j*9 + r] = 0.f;
    }
  }
  __syncthreads();

  const int tp = s + tid;
  if (tp < TW_){
    float z[8];
#pragma unroll
    for (int r = 0; r < 8; ++r) z[r] = zz[(tid + 32)*9 + r];
    float cv = 0.f;
#pragma unroll
    for (int r = 0; r < 8; ++r) cv += cstf[1280 + r] * z[r];
    cv *= cv;
    float acc = 0.f;
#pragma unroll 4
    for (int w = 0; w < 32; ++w){
      float fj = 0.f;
#pragma unroll
      for (int r = 0; r < 8; ++r) fj += z[r] * cstf[1024 + r*32 + w];
      acc += fj * (xm[tid + w] - mm[tid + w]);
    }
    out0[(size_t)b*TW_ + tp] = mm[tid + 32] - cv * acc;
  }
}

extern "C" void kernel_launch(void* const* d_in, const int* in_sizes, int n_in,
                              void* d_out, int out_size, void* d_ws, size_t ws_size,
                              hipStream_t stream)
{
  const float* x   = (const float*)d_in[0];
  const float* cw0 = (const float*)d_in[1];
  const float* cb0 = (const float*)d_in[2];
  const float* cw1 = (const float*)d_in[3];
  const float* cb1 = (const float*)d_in[4];
  const float* cw2 = (const float*)d_in[5];
  const float* cb2 = (const float*)d_in[6];
  const float* cw3 = (const float*)d_in[7];
  const float* cb3 = (const float*)d_in[8];
  const float* cw4 = (const float*)d_in[9];
  const float* cb4 = (const float*)d_in[10];
  const float* mw0 = (const float*)d_in[11];
  const float* mb0 = (const float*)d_in[12];
  const float* mw1 = (const float*)d_in[13];
  const float* mb1 = (const float*)d_in[14];
  const float* mw2 = (const float*)d_in[15];
  const float* mb2 = (const float*)d_in[16];
  const float* sct = (const float*)d_in[17];
  const float* fish= (const float*)d_in[18];
  const float* gum = (const float*)d_in[19];

  float* out0   = (float*)d_out;               // _mus: (16, 16352)
  float* out_gz = out0 + NB*TW_;               // gen_z: (16, 8, 16384)
  ushort* wimg  = (ushort*)d_ws;               // weight image (~113 KB)
  float* h4ws   = (float*)((char*)d_ws + 131072);   // (16,8,16384) fp32 = 8.4 MB
  const float* cstf = (const float*)(wimg + WIMG_CST);

  kW<<<114, 256, 0, stream>>>(cw1, cw2, cw3, cw4, cw0, cb0, cb1, cb2, cb3, cb4,
                              mw0, mb0, mw1, mb1, mw2, mb2, fish, sct, wimg);

  dim3 gA(NTILE, NB);                          // (103, 16)
  kA<<<gA, NT, 0, stream>>>(x, wimg, h4ws);
  dim3 gB(T_/256, NB);                         // (64, 16)
  kB2<<<gB, 256, 0, stream>>>(x, gum, h4ws, cstf, out0, out_gz);
}

// Round 13
// 205.541 us; speedup vs baseline: 1.4702x; 1.0449x over previous
//
#include <hip/hip_runtime.h>
#include <hip/hip_bf16.h>

#define NT 512
#define TT 160      // outputs per tile
#define NTILE 103   // ceil(T/TT)
#define RA 190      // bufA rows (TT+30)
#define RB 188      // bufB rows (TT+28)
#define NB 16
#define T_ 16384
#define W_ 32
#define TW_ (T_ - W_)
#define SLOPE_C 0.22916666666666666f

// weight image in workspace (ushort offsets), SWIZZLED rows:
//   0: W1 hi/lo   16384: W2   32768: W3   49152: W4 (rows 8..15 zeroed)
//   53248: consts float[1536]
#define WIMG_W4   49152
#define WIMG_CST  53248

typedef short v8s __attribute__((ext_vector_type(8)));
typedef float v4f __attribute__((ext_vector_type(4)));

__device__ __forceinline__ float rr(float v){ return v >= 0.f ? v : v * SLOPE_C; }
__device__ __forceinline__ ushort f2bs(float f){ __hip_bfloat16 h = __float2bfloat16(f); return *(ushort*)&h; }
__device__ __forceinline__ float bs2f(ushort u){ union{unsigned i; float f;} v; v.i = ((unsigned)u) << 16; return v.f; }

__device__ __forceinline__ int agr(int p, int gi){ return p*128 + ((gi ^ (p & 15)) << 3); }
__device__ __forceinline__ int widx(int wr, int ci){
  return wr*64 + ((((ci >> 3) ^ (wr & 7)) << 3) | (ci & 7));
}

// ---------------- pre-kernel: swizzled hi/lo weight image + consts ----------------
__global__ __launch_bounds__(256) void kW(
    const float* __restrict__ cw1, const float* __restrict__ cw2,
    const float* __restrict__ cw3, const float* __restrict__ cw4,
    const float* __restrict__ cw0, const float* __restrict__ cb0,
    const float* __restrict__ cb1, const float* __restrict__ cb2,
    const float* __restrict__ cb3, const float* __restrict__ cb4,
    const float* __restrict__ mw0, const float* __restrict__ mb0,
    const float* __restrict__ mw1, const float* __restrict__ mb1,
    const float* __restrict__ mw2, const float* __restrict__ mb2,
    const float* __restrict__ fish, const float* __restrict__ sct,
    ushort* __restrict__ wimg)
{
  const int id = blockIdx.x*256 + threadIdx.x;
  if (id < 24576){                       // W1..W3: (64,64,2)
    int l = id >> 13, e = id & 8191;
    const float* src = (l == 0) ? cw1 : ((l == 1) ? cw2 : cw3);
    int c = e >> 7, rem = e & 127, ci = rem >> 1, k = rem & 1;
    float v = src[e];
    ushort h = f2bs(v), lo = f2bs(v - bs2f(h));
    int ix = widx(k*64 + c, ci);
    wimg[l*16384 + ix] = h;
    wimg[l*16384 + 8192 + ix] = lo;
  } else if (id < 25600){                // W4 rows 0..7
    int e = id - 24576;
    int c = e >> 7, rem = e & 127, ci = rem >> 1, k = rem & 1;
    float v = cw4[e];
    ushort h = f2bs(v), lo = f2bs(v - bs2f(h));
    int ix = widx(k*16 + c, ci);
    wimg[WIMG_W4 + ix] = h;
    wimg[WIMG_W4 + 2048 + ix] = lo;
  } else if (id < 27648){                // W4 zero rows 8..15
    int e = id - 25600;
    int pl = e >> 10, rem = e & 1023, k = rem >> 9, r2 = rem & 511;
    int m = 8 + (r2 >> 6), ci = r2 & 63;
    wimg[WIMG_W4 + pl*2048 + widx(k*16 + m, ci)] = 0;
  } else if (id < 29184){                // consts float[1536]
    int e = id - 27648;
    float v = 0.f;
    if      (e < 256)  v = mw0[e];
    else if (e < 512)  v = mw1[e - 256];
    else if (e < 528)  v = mw2[e - 512];
    else if (e < 544)  v = mb0[e - 528];
    else if (e < 560)  v = mb1[e - 544];
    else if (e < 561)  v = mb2[0];
    else if (e >= 576 && e < 584)  v = cb4[e - 576];
    else if (e >= 592 && e < 720)  v = cw0[e - 592];
    else if (e >= 720 && e < 784)  v = cb0[e - 720];
    else if (e >= 784 && e < 848)  v = cb1[e - 784];
    else if (e >= 848 && e < 912)  v = cb2[e - 848];
    else if (e >= 912 && e < 976)  v = cb3[e - 912];
    else if (e >= 1024 && e < 1280) v = fish[e - 1024];
    else if (e >= 1280 && e < 1288) v = sct[e - 1280];
    ((float*)(wimg + WIMG_CST))[e] = v;
  }
}

// 64->64 dilated conv on MFMA, hi/lo bf16 (3-term), weights from swizzled LDS.
// Caller guards: only waves 0..5 enter. Wave w covers positions [w*32, w*32+32).
// bias_f: fp32 LDS array (16B aligned) pre-loaded into accumulators.
template<int D, int NSRC, int NDST>
__device__ __forceinline__ void mfma_layer(const ushort* __restrict__ src,
    ushort* __restrict__ dst, const ushort* __restrict__ wlds,
    const float* __restrict__ bias_f, int tid)
{
  const int wave = tid >> 6;
  const int lane = tid & 63;
  const int n = lane & 15, quad = lane >> 4;
  const int p0 = wave * 32;

  v4f acc[8];
#pragma unroll
  for (int mt = 0; mt < 4; ++mt){
    v4f bv = *(const v4f*)(bias_f + mt*16 + quad*4);
    acc[mt] = bv; acc[4 + mt] = bv;
  }

#pragma unroll
  for (int tap = 0; tap < 2; ++tap){
    const ushort* rp[2]; int sw[2];
#pragma unroll
    for (int nt = 0; nt < 2; ++nt){
      int p = p0 + nt*16 + n + tap*D;
      if (p >= NSRC) p = NSRC - 1;            // clamp: invalid outputs only
      rp[nt] = src + p*128; sw[nt] = p & 15;
    }
    v8s wh[2][4], wl[2][4], ah[2][2], al[2][2];
#pragma unroll
    for (int kb = 0; kb < 2; ++kb){
      const int kg = kb*4 + quad;
#pragma unroll
      for (int mt = 0; mt < 4; ++mt){
        int wr = tap*64 + mt*16 + n;
        int base = wr*64 + ((kg ^ (wr & 7)) << 3);
        wh[kb][mt] = *(const v8s*)(wlds + base);
        wl[kb][mt] = *(const v8s*)(wlds + 8192 + base);
      }
#pragma unroll
      for (int nt = 0; nt < 2; ++nt){
        ah[kb][nt] = *(const v8s*)(rp[nt] + ((kg ^ sw[nt]) << 3));
        al[kb][nt] = *(const v8s*)(rp[nt] + (((8 + kg) ^ sw[nt]) << 3));
      }
    }
#pragma unroll
    for (int kb = 0; kb < 2; ++kb)
#pragma unroll
      for (int nt = 0; nt < 2; ++nt)
#pragma unroll
        for (int mt = 0; mt < 4; ++mt){
          v4f a = acc[nt*4 + mt];
          a = __builtin_amdgcn_mfma_f32_16x16x32_bf16(wh[kb][mt], ah[kb][nt], a, 0, 0, 0);
          a = __builtin_amdgcn_mfma_f32_16x16x32_bf16(wh[kb][mt], al[kb][nt], a, 0, 0, 0);
          a = __builtin_amdgcn_mfma_f32_16x16x32_bf16(wl[kb][mt], ah[kb][nt], a, 0, 0, 0);
          acc[nt*4 + mt] = a;
        }
  }

  // epilogue: D col=lane&15 (pos), row=quad*4+r (cout); trunc hi/lo, b64 stores
#pragma unroll
  for (int nt = 0; nt < 2; ++nt){
    int p = p0 + nt*16 + n;
    if (p < NDST){
      const int sw = p & 15;
      ushort* drow = dst + p*128;
#pragma unroll
      for (int mt = 0; mt < 4; ++mt){
        float y0 = rr(acc[nt*4 + mt][0]);
        float y1 = rr(acc[nt*4 + mt][1]);
        float y2 = rr(acc[nt*4 + mt][2]);
        float y3 = rr(acc[nt*4 + mt][3]);
        unsigned u0 = __float_as_uint(y0), u1 = __float_as_uint(y1);
        unsigned u2 = __float_as_uint(y2), u3 = __float_as_uint(y3);
        uint2 hp, lp;
        hp.x = (u0 >> 16) | (u1 & 0xffff0000u);
        hp.y = (u2 >> 16) | (u3 & 0xffff0000u);
        float r0 = y0 - __uint_as_float(u0 & 0xffff0000u);
        float r1 = y1 - __uint_as_float(u1 & 0xffff0000u);
        float r2 = y2 - __uint_as_float(u2 & 0xffff0000u);
        float r3 = y3 - __uint_as_float(u3 & 0xffff0000u);
        lp.x = (__float_as_uint(r0) >> 16) | (__float_as_uint(r1) & 0xffff0000u);
        lp.y = (__float_as_uint(r2) >> 16) | (__float_as_uint(r3) & 0xffff0000u);
        int c0 = mt*16 + quad*4;
        int gh = (c0 >> 3) ^ sw;
        int gl = (8 + (c0 >> 3)) ^ sw;
        *(uint2*)(drow + (gh << 3) + (c0 & 7)) = hp;
        *(uint2*)(drow + (gl << 3) + (c0 & 7)) = lp;
      }
    }
  }
}

// stager: linear 16B copy global image -> LDS, 128 threads
__device__ __forceinline__ void stageW(ushort* dst, const ushort* src, int n8, int t128){
  for (int i = t128; i < n8; i += 128)
    *(v8s*)(dst + i*8) = *(const v8s*)(src + i*8);
}

__global__ __launch_bounds__(NT) void kA(
    const float* __restrict__ x, const ushort* __restrict__ wimg,
    float* __restrict__ h4ws)
{
  __shared__ __align__(16) ushort bufA[RA*128];    // 48,640 B
  __shared__ __align__(16) ushort bufB[RB*128];    // 48,128 B
  __shared__ __align__(16) ushort r1[16384];       // 32,768 B
  __shared__ __align__(16) ushort r2[16384];       // 32,768 B
  __shared__ __align__(16) float  cst[264];        //  1,056 B  -> 163,360 B

  const float* cstf = (const float*)(wimg + WIMG_CST);
  float* xbuf = (float*)bufB;            // alias: dead before L1 writes bufB

  const int tile = blockIdx.x, b = blockIdx.y;
  const int o0 = tile * TT;
  const int core = (T_ - o0 < TT) ? (T_ - o0) : TT;
  const int tid = threadIdx.x;
  const int wave = tid >> 6;

  // Phase A: stage x, W1->r1, biases
  const int nx = core + 31;
  for (int i = tid; i < nx; i += NT){
    int g = o0 + i;
    xbuf[i] = (g >= 31) ? x[(size_t)b*T_ + g - 31] : 0.f;
  }
  for (int i = tid; i < 2048; i += NT)
    *(v8s*)(r1 + i*8) = *(const v8s*)(wimg + i*8);
  for (int i = tid; i < 264; i += NT){
    float v;
    if (i < 192) v = cstf[784 + i];            // cb1,cb2,cb3
    else if (i < 200) v = cstf[576 + i - 192]; // cb4
    else v = cstf[720 + i - 200];              // cb0
    cst[i] = v;
  }
  __syncthreads();

  // Layer0 (1->64, d=1): paired u32 writes, zero halo, trunc hi/lo split
  {
    const int n0 = core + 30;
    for (int i = tid; i < RA*32; i += NT){
      int p = i >> 5, c = (i & 31)*2;
      float y0 = 0.f, y1 = 0.f;
      if (p < n0){
        float xp = xbuf[p], xq = xbuf[p + 1];
        y0 = rr(cst[200 + c]     + cstf[592 + 2*c]*xp + cstf[593 + 2*c]*xq);
        y1 = rr(cst[201 + c]     + cstf[594 + 2*c]*xp + cstf[595 + 2*c]*xq);
      }
      unsigned q0 = __float_as_uint(y0), q1 = __float_as_uint(y1);
      *(unsigned*)(bufA + agr(p, c >> 3) + (c & 7)) = (q0 >> 16) | (q1 & 0xffff0000u);
      float r0v = y0 - __uint_as_float(q0 & 0xffff0000u);
      float r1v = y1 - __uint_as_float(q1 & 0xffff0000u);
      *(unsigned*)(bufA + agr(p, 8 + (c >> 3)) + (c & 7)) =
          (__float_as_uint(r0v) >> 16) | (__float_as_uint(r1v) & 0xffff0000u);
    }
  }
  __syncthreads();

  // L1 compute (r1) || stage W2->r2
  if (wave < 6) mfma_layer<2, RA, RB>(bufA, bufB, r1, cst, tid);
  else          stageW(r2, wimg + 16384, 2048, tid - 384);
  __syncthreads();
  // L2 compute (r2) || stage W3->r1   [NSRC=188 = L1's NDST]
  if (wave < 6) mfma_layer<4, 188, 184>(bufB, bufA, r2, cst + 64, tid);
  else          stageW(r1, wimg + 32768, 2048, tid - 384);
  __syncthreads();
  // L3 compute (r1) || stage W4->r2
  if (wave < 6) mfma_layer<8, 184, 176>(bufA, bufB, r1, cst + 128, tid);
  else          stageW(r2, wimg + WIMG_W4, 512, tid - 384);
  __syncthreads();

  // Layer4 (64->8, d=16) on MFMA from r2; epilogue straight to global h4ws
  if (wave < 5){
    const int lane = tid & 63;
    const int n = lane & 15, quad = lane >> 4;
    const int p0 = wave * 32;
    v4f acc2[2];
    const v4f vz = {0.f, 0.f, 0.f, 0.f};
    acc2[0] = vz; acc2[1] = vz;
#pragma unroll
    for (int tap = 0; tap < 2; ++tap){
#pragma unroll
      for (int kb = 0; kb < 2; ++kb){
        const int kg = kb*4 + quad;
        int wr = tap*16 + n;
        int base = wr*64 + ((kg ^ (wr & 7)) << 3);
        v8s wh = *(const v8s*)(r2 + base);
        v8s wl = *(const v8s*)(r2 + 2048 + base);
#pragma unroll
        for (int nt = 0; nt < 2; ++nt){
          int p = p0 + nt*16 + n + tap*16;
          if (p >= 176) p = 175;
          v8s ah = *(const v8s*)(bufB + agr(p, kg));
          v8s al = *(const v8s*)(bufB + agr(p, 8 + kg));
          v4f a = acc2[nt];
          a = __builtin_amdgcn_mfma_f32_16x16x32_bf16(wh, ah, a, 0, 0, 0);
          a = __builtin_amdgcn_mfma_f32_16x16x32_bf16(wh, al, a, 0, 0, 0);
          a = __builtin_amdgcn_mfma_f32_16x16x32_bf16(wl, ah, a, 0, 0, 0);
          acc2[nt] = a;
        }
      }
    }
#pragma unroll
    for (int nt = 0; nt < 2; ++nt){
      int p = p0 + nt*16 + n;
      if (p < core && quad < 2){
#pragma unroll
        for (int r = 0; r < 4; ++r){
          int c = quad*4 + r;
          h4ws[(size_t)(b*8 + c)*T_ + o0 + p] = rr(acc2[nt][r] + cst[192 + c]);
        }
      }
    }
  }
}

// softmax + MLP + windowed correction; MLP/fish/sct via uniform global (s_load)
__global__ __launch_bounds__(256) void kB2(
    const float* __restrict__ x, const float* __restrict__ gum,
    const float* __restrict__ h4, const float* __restrict__ cstf,
    float* __restrict__ out0, float* __restrict__ out_gz)
{
  __shared__ float xm[288];
  __shared__ float mm[288];
  __shared__ float zz[288*9];
  const int b = blockIdx.y;
  const int s = blockIdx.x * 256;
  const int tid = threadIdx.x;

  for (int i = tid; i < 288; i += 256){
    int g = s + i;
    xm[i] = (g < T_) ? x[(size_t)b*T_ + g] : 0.f;
  }

#pragma unroll
  for (int pass = 0; pass < 2; ++pass){
    int j = pass == 0 ? tid : 256 + tid;
    if (pass == 1 && tid >= 32) break;
    int t = s + j;
    if (t < T_){
      float l[8];
#pragma unroll
      for (int r = 0; r < 8; ++r) l[r] = h4[(size_t)(b*8 + r)*T_ + t];
      float gv[8];
      *(float4*)&gv[0] = *(const float4*)(gum + (size_t)(b*T_ + t)*8);
      *(float4*)&gv[4] = *(const float4*)(gum + (size_t)(b*T_ + t)*8 + 4);
      float sv[8], mx = -1e30f;
#pragma unroll
      for (int r = 0; r < 8; ++r){ sv[r] = (l[r] + gv[r]) * 10.0f; mx = fmaxf(mx, sv[r]); }
      float e[8], sum = 0.f;
#pragma unroll
      for (int r = 0; r < 8; ++r){ e[r] = __expf(sv[r] - mx); sum += e[r]; }
      float inv = 1.0f / sum;
      float z[8];
#pragma unroll
      for (int r = 0; r < 8; ++r){
        z[r] = e[r] * inv;
        out_gz[(size_t)(b*8 + r)*T_ + t] = z[r];
        zz[j*9 + r] = z[r];
      }
      float m0[16];
#pragma unroll
      for (int o = 0; o < 16; ++o){
        float a = cstf[528 + o];
#pragma unroll
        for (int i = 0; i < 8; ++i) a += cstf[o*16 + i] * z[i];
#pragma unroll
        for (int i = 0; i < 8; ++i) a += cstf[o*16 + 8 + i] * l[i];
        m0[o] = rr(a);
      }
      float m1[16];
#pragma unroll
      for (int o = 0; o < 16; ++o){
        float a = cstf[544 + o];
#pragma unroll
        for (int i = 0; i < 16; ++i) a += cstf[256 + o*16 + i] * m0[i];
        m1[o] = rr(a);
      }
      float mu = cstf[560];
#pragma unroll
      for (int i = 0; i < 16; ++i) mu += cstf[512 + i] * m1[i];
      mm[j] = mu;
    } else {
      mm[j] = 0.f;
#pragma unroll
      for (int r = 0; r < 8; ++r) zz[j*9 + r] = 0.f;
    }
  }
  __syncthreads();

  const int tp = s + tid;
  if (tp < TW_){
    float z[8];
#pragma unroll
    for (int r = 0; r < 8; ++r) z[r] = zz[(tid + 32)*9 + r];
    float cv = 0.f;
#pragma unroll
    for (int r = 0; r < 8; ++r) cv += cstf[1280 + r] * z[r];
    cv *= cv;
    float acc = 0.f;
#pragma unroll 4
    for (int w = 0; w < 32; ++w){
      float fj = 0.f;
#pragma unroll
      for (int r = 0; r < 8; ++r) fj += z[r] * cstf[1024 + r*32 + w];
      acc += fj * (xm[tid + w] - mm[tid + w]);
    }
    out0[(size_t)b*TW_ + tp] = mm[tid + 32] - cv * acc;
  }
}

extern "C" void kernel_launch(void* const* d_in, const int* in_sizes, int n_in,
                              void* d_out, int out_size, void* d_ws, size_t ws_size,
                              hipStream_t stream)
{
  const float* x   = (const float*)d_in[0];
  const float* cw0 = (const float*)d_in[1];
  const float* cb0 = (const float*)d_in[2];
  const float* cw1 = (const float*)d_in[3];
  const float* cb1 = (const float*)d_in[4];
  const float* cw2 = (const float*)d_in[5];
  const float* cb2 = (const float*)d_in[6];
  const float* cw3 = (const float*)d_in[7];
  const float* cb3 = (const float*)d_in[8];
  const float* cw4 = (const float*)d_in[9];
  const float* cb4 = (const float*)d_in[10];
  const float* mw0 = (const float*)d_in[11];
  const float* mb0 = (const float*)d_in[12];
  const float* mw1 = (const float*)d_in[13];
  const float* mb1 = (const float*)d_in[14];
  const float* mw2 = (const float*)d_in[15];
  const float* mb2 = (const float*)d_in[16];
  const float* sct = (const float*)d_in[17];
  const float* fish= (const float*)d_in[18];
  const float* gum = (const float*)d_in[19];

  float* out0   = (float*)d_out;               // _mus: (16, 16352)
  float* out_gz = out0 + NB*TW_;               // gen_z: (16, 8, 16384)
  ushort* wimg  = (ushort*)d_ws;               // weight image (~113 KB)
  float* h4ws   = (float*)((char*)d_ws + 131072);   // (16,8,16384) fp32 = 8.4 MB
  const float* cstf = (const float*)(wimg + WIMG_CST);

  kW<<<114, 256, 0, stream>>>(cw1, cw2, cw3, cw4, cw0, cb0, cb1, cb2, cb3, cb4,
                              mw0, mb0, mw1, mb1, mw2, mb2, fish, sct, wimg);

  dim3 gA(NTILE, NB);                          // (103, 16)
  kA<<<gA, NT, 0, stream>>>(x, wimg, h4ws);
  dim3 gB(T_/256, NB);                         // (64, 16)
  kB2<<<gB, 256, 0, stream>>>(x, gum, h4ws, cstf, out0, out_gz);
}